// Round 1
// baseline (1878.460 us; speedup 1.0000x reference)
//
#include <hip/hip_runtime.h>
#include <math.h>

// Problem constants (fixed by setup_inputs)
#define N_TOK 16384   // B*S = 4*4096
#define D_DIM 2048
#define H_DIM 256
#define E_NUM 5
#define R_DIM 16
#define ER 80         // E*R

// ---------------------------------------------------------------------------
// K1: router.  h = silu(x@W1 + b1); logits = h@W2 + b2; top-2 + pair-normalized
// weights.  One block = 32 tokens, 256 threads (thread = H column).
// x is read via wave-uniform addresses -> scalar loads (SMEM pipe), W1 is
// streamed coalesced (one dword per lane per k).  acc lives in 32 VGPRs.
// ---------------------------------------------------------------------------
__global__ __launch_bounds__(256) void router_kernel(
    const float* __restrict__ x, const float* __restrict__ W1,
    const float* __restrict__ b1, const float* __restrict__ W2,
    const float* __restrict__ b2, int* __restrict__ idx_out,
    float* __restrict__ wts_out) {
  const int t = threadIdx.x;
  const int c = t;                       // H column 0..255
  const int tok0 = blockIdx.x * 32;
  const float* xb = x + (size_t)tok0 * D_DIM;

  float acc[32];
#pragma unroll
  for (int s = 0; s < 32; ++s) acc[s] = 0.f;

  for (int k0 = 0; k0 < D_DIM; k0 += 8) {
    float w[8];
#pragma unroll
    for (int j = 0; j < 8; ++j) w[j] = W1[(size_t)(k0 + j) * H_DIM + c];
#pragma unroll
    for (int s = 0; s < 32; ++s) {
      const float* xr = xb + (size_t)s * D_DIM + k0;  // wave-uniform -> s_load
#pragma unroll
      for (int j = 0; j < 8; ++j) acc[s] = fmaf(xr[j], w[j], acc[s]);
    }
  }

  // Epilogue: silu, project to E logits via shuffle reduction.
  const int lane = t & 63;
  const int wv = t >> 6;
  __shared__ float red[32][4][5];
  const float bb = b1[c];
  float w2r[5];
#pragma unroll
  for (int e = 0; e < 5; ++e) w2r[e] = W2[c * 5 + e];

  for (int s = 0; s < 32; ++s) {
    const float a = acc[s] + bb;
    const float hs = a / (1.f + expf(-a));   // silu, fp32
    float p[5];
#pragma unroll
    for (int e = 0; e < 5; ++e) p[e] = hs * w2r[e];
#pragma unroll
    for (int off = 32; off >= 1; off >>= 1) {
#pragma unroll
      for (int e = 0; e < 5; ++e) p[e] += __shfl_xor(p[e], off, 64);
    }
    if (lane == 0) {
#pragma unroll
      for (int e = 0; e < 5; ++e) red[s][wv][e] = p[e];
    }
  }
  __syncthreads();

  if (t < 32) {
    const int s = t;
    float l[5];
#pragma unroll
    for (int e = 0; e < 5; ++e)
      l[e] = b2[e] + red[s][0][e] + red[s][1][e] + red[s][2][e] + red[s][3][e];
    // top-2 by logits (== top-2 by softmax, monotone); strict > matches
    // jax.lax.top_k tie order (lower index first).
    int e0 = 0;
#pragma unroll
    for (int e = 1; e < 5; ++e) if (l[e] > l[e0]) e0 = e;
    int e1 = (e0 == 0) ? 1 : 0;
#pragma unroll
    for (int e = 0; e < 5; ++e) if (e != e0 && l[e] > l[e1]) e1 = e;
    // pair-normalized softmax weights: exp(l0)/(exp(l0)+exp(l1)) exactly
    const float q = expf(l[e1] - l[e0]);   // <= 1, stable
    const float inv = 1.f / (1.f + q);
    const int tok = tok0 + s;
    ((int2*)idx_out)[tok] = make_int2(e0, e1);
    ((float2*)wts_out)[tok] = make_float2(inv, q * inv);
  }
}

// ---------------------------------------------------------------------------
// K2: low = x @ A_e for all experts (dense, like the reference), immediately
// masked+scaled into P[N][80]:  P[s][e*16+r] = (e selected ? 2*w : 0)*low.
// Grid: (64 token-blocks of 256 tokens, 5 experts).  Thread tile 4 tokens x
// 4 r-cols via ds_read_b128 from a transposed x tile.
// ---------------------------------------------------------------------------
__global__ __launch_bounds__(256) void low_kernel(
    const float* __restrict__ x, const float* __restrict__ A,
    const int* __restrict__ idx, const float* __restrict__ wts,
    float* __restrict__ P) {
  __shared__ float xT[32][260];   // [k][token], pad 260 keeps 16B align, ~2-way banks
  __shared__ float aT[32][16];    // [k][r]
  const int t = threadIdx.x;
  const int e = blockIdx.y;
  const int tok0 = blockIdx.x * 256;
  const int tc = t & 3;           // r group: cols tc*4..+3
  const int tr = t >> 2;          // token group: tokens tr*4..+3
  const float* Ae = A + (size_t)e * D_DIM * R_DIM;

  float acc[4][4];
#pragma unroll
  for (int i = 0; i < 4; ++i)
#pragma unroll
    for (int j = 0; j < 4; ++j) acc[i][j] = 0.f;

  const int skk = t >> 3;  // staging k 0..31
  const int ssi = t & 7;   // staging token phase 0..7

  for (int k0 = 0; k0 < D_DIM; k0 += 32) {
    __syncthreads();
#pragma unroll
    for (int i = 0; i < 32; ++i) {
      const int s = ssi + (i << 3);
      xT[skk][s] = x[(size_t)(tok0 + s) * D_DIM + k0 + skk];
    }
    if (t < 128) {
      const float4 av =
          *(const float4*)(Ae + (size_t)(k0 + (t >> 2)) * R_DIM + ((t & 3) << 2));
      *(float4*)&aT[t >> 2][(t & 3) << 2] = av;
    }
    __syncthreads();
#pragma unroll
    for (int kk = 0; kk < 32; ++kk) {
      const float4 xv = *(const float4*)&xT[kk][tr << 2];
      const float4 av = *(const float4*)&aT[kk][tc << 2];
      acc[0][0] = fmaf(xv.x, av.x, acc[0][0]);
      acc[0][1] = fmaf(xv.x, av.y, acc[0][1]);
      acc[0][2] = fmaf(xv.x, av.z, acc[0][2]);
      acc[0][3] = fmaf(xv.x, av.w, acc[0][3]);
      acc[1][0] = fmaf(xv.y, av.x, acc[1][0]);
      acc[1][1] = fmaf(xv.y, av.y, acc[1][1]);
      acc[1][2] = fmaf(xv.y, av.z, acc[1][2]);
      acc[1][3] = fmaf(xv.y, av.w, acc[1][3]);
      acc[2][0] = fmaf(xv.z, av.x, acc[2][0]);
      acc[2][1] = fmaf(xv.z, av.y, acc[2][1]);
      acc[2][2] = fmaf(xv.z, av.z, acc[2][2]);
      acc[2][3] = fmaf(xv.z, av.w, acc[2][3]);
      acc[3][0] = fmaf(xv.w, av.x, acc[3][0]);
      acc[3][1] = fmaf(xv.w, av.y, acc[3][1]);
      acc[3][2] = fmaf(xv.w, av.z, acc[3][2]);
      acc[3][3] = fmaf(xv.w, av.w, acc[3][3]);
    }
  }

#pragma unroll
  for (int i = 0; i < 4; ++i) {
    const int s = tok0 + (tr << 2) + i;
    const int2 id = ((const int2*)idx)[s];
    const float2 wv2 = ((const float2*)wts)[s];
    const float scale =
        (e == id.x) ? 2.f * wv2.x : ((e == id.y) ? 2.f * wv2.y : 0.f);
    float4 o;
    o.x = scale * acc[i][0];
    o.y = scale * acc[i][1];
    o.z = scale * acc[i][2];
    o.w = scale * acc[i][3];
    *(float4*)&P[(size_t)s * ER + e * R_DIM + (tc << 2)] = o;
  }
}

// ---------------------------------------------------------------------------
// K3: out = base + P[N,80] @ B[80,2048].  B input layout [E][R][D] is exactly
// [80][2048] with row index e*16+r == P column order.  Thread: 16 tokens x 4
// cols; P rows read via wave-uniform addresses (scalar loads), B via float4.
// ---------------------------------------------------------------------------
__global__ __launch_bounds__(256) void combine_kernel(
    const float* __restrict__ P, const float* __restrict__ Bm,
    const float* __restrict__ base, float* __restrict__ out) {
  const int t = threadIdx.x;
  const int wg = __builtin_amdgcn_readfirstlane(t >> 6);  // wave-uniform
  const int c4 = ((blockIdx.x & 7) << 8) + ((t & 63) << 2);
  const int tok0 = ((blockIdx.x >> 3) << 6) + (wg << 4);

  float4 acc[16];
#pragma unroll
  for (int i = 0; i < 16; ++i) acc[i] = make_float4(0.f, 0.f, 0.f, 0.f);

  for (int k0 = 0; k0 < ER; k0 += 4) {
    const float4 bv0 = *(const float4*)(Bm + (size_t)(k0 + 0) * D_DIM + c4);
    const float4 bv1 = *(const float4*)(Bm + (size_t)(k0 + 1) * D_DIM + c4);
    const float4 bv2 = *(const float4*)(Bm + (size_t)(k0 + 2) * D_DIM + c4);
    const float4 bv3 = *(const float4*)(Bm + (size_t)(k0 + 3) * D_DIM + c4);
#pragma unroll
    for (int i = 0; i < 16; ++i) {
      const float* pr = P + (size_t)(tok0 + i) * ER + k0;  // uniform -> s_load
      const float p0 = pr[0], p1 = pr[1], p2 = pr[2], p3 = pr[3];
      acc[i].x = fmaf(p0, bv0.x, fmaf(p1, bv1.x, fmaf(p2, bv2.x, fmaf(p3, bv3.x, acc[i].x))));
      acc[i].y = fmaf(p0, bv0.y, fmaf(p1, bv1.y, fmaf(p2, bv2.y, fmaf(p3, bv3.y, acc[i].y))));
      acc[i].z = fmaf(p0, bv0.z, fmaf(p1, bv1.z, fmaf(p2, bv2.z, fmaf(p3, bv3.z, acc[i].z))));
      acc[i].w = fmaf(p0, bv0.w, fmaf(p1, bv1.w, fmaf(p2, bv2.w, fmaf(p3, bv3.w, acc[i].w))));
    }
  }

#pragma unroll
  for (int i = 0; i < 16; ++i) {
    const size_t o = (size_t)(tok0 + i) * D_DIM + c4;
    const float4 b = *(const float4*)(base + o);
    float4 r;
    r.x = acc[i].x + b.x;
    r.y = acc[i].y + b.y;
    r.z = acc[i].z + b.z;
    r.w = acc[i].w + b.w;
    *(float4*)(out + o) = r;
  }
}

// ---------------------------------------------------------------------------
extern "C" void kernel_launch(void* const* d_in, const int* in_sizes, int n_in,
                              void* d_out, int out_size, void* d_ws,
                              size_t ws_size, hipStream_t stream) {
  const float* x   = (const float*)d_in[0];
  const float* bo  = (const float*)d_in[1];
  const float* A   = (const float*)d_in[2];
  const float* Bm  = (const float*)d_in[3];
  const float* W1  = (const float*)d_in[4];
  const float* b1  = (const float*)d_in[5];
  const float* W2  = (const float*)d_in[6];
  const float* b2  = (const float*)d_in[7];
  float* out = (float*)d_out;

  char* ws = (char*)d_ws;
  int*   idx = (int*)ws;                       // [N][2] int32   (128 KiB)
  float* wts = (float*)(ws + 131072);          // [N][2] f32     (128 KiB)
  float* P   = (float*)(ws + 262144);          // [N][80] f32    (5.25 MiB)

  router_kernel<<<N_TOK / 32, 256, 0, stream>>>(x, W1, b1, W2, b2, idx, wts);
  low_kernel<<<dim3(N_TOK / 256, E_NUM), 256, 0, stream>>>(x, A, idx, wts, P);
  combine_kernel<<<(N_TOK / 64) * (D_DIM / 256), 256, 0, stream>>>(P, Bm, bo, out);
}

// Round 2
// 704.712 us; speedup vs baseline: 2.6656x; 2.6656x over previous
//
#include <hip/hip_runtime.h>
#include <math.h>

// Problem constants (fixed by setup_inputs)
#define N_TOK 16384   // B*S
#define D_DIM 2048
#define H_DIM 256
#define E_NUM 5
#define R_DIM 16
#define ER 80         // E*R

// ---------------------------------------------------------------------------
// xgemm: grid (N_TOK/64, 3).
//   y in {0,1}: h[:, y*128 .. +127] = silu(x @ W1 + b1)   (64 tok x 128 col)
//   y == 2   : P[:, 0..79]          = x @ A'              (64 tok x 80 col)
// A'[d][e*16+r] = A[e][d][r]; P columns ordered e*16+r to match B' rows.
// LDS-tiled fp32 GEMM, K-chunk 32. 768 blocks = 3/CU exactly.
// ---------------------------------------------------------------------------
__global__ __launch_bounds__(256) void xgemm_kernel(
    const float* __restrict__ x, const float* __restrict__ W1,
    const float* __restrict__ b1, const float* __restrict__ A,
    float* __restrict__ h, float* __restrict__ P) {
  __shared__ float xT[32][68];    // [k][token], stride 68 floats (rows 16B-aligned)
  __shared__ float bT[32][132];   // [k][col], stride 132 floats (rows 16B-aligned)
  const int t = threadIdx.x;
  const int cb = blockIdx.y;
  const int tok0 = blockIdx.x * 64;
  const int tx = t & 15;
  const int ty = t >> 4;          // 16 groups of 4 tokens
  const int sk = (t & 7) << 2;    // x-staging k offset
  const int sr = t >> 3;          // x-staging token

  if (cb < 2) {
    const int col0 = cb * 128;
    float acc[4][8];
#pragma unroll
    for (int i = 0; i < 4; ++i)
#pragma unroll
      for (int j = 0; j < 8; ++j) acc[i][j] = 0.f;

    for (int k0 = 0; k0 < D_DIM; k0 += 32) {
      __syncthreads();
      // stage x tile [64 tok][32 k] -> transposed xT[k][tok]
#pragma unroll
      for (int p = 0; p < 2; ++p) {
        const int s = sr + (p << 5);
        float xv[4];
        *(float4*)xv = *(const float4*)(x + (size_t)(tok0 + s) * D_DIM + k0 + sk);
#pragma unroll
        for (int c = 0; c < 4; ++c) xT[sk + c][s] = xv[c];
      }
      // stage W1 tile [32 k][128 col]
      {
        const int kk = t >> 3;
        const int c0 = (t & 7) << 4;
#pragma unroll
        for (int u = 0; u < 4; ++u) {
          *(float4*)&bT[kk][c0 + (u << 2)] =
              *(const float4*)(W1 + (size_t)(k0 + kk) * H_DIM + col0 + c0 + (u << 2));
        }
      }
      __syncthreads();
#pragma unroll
      for (int kk = 0; kk < 32; ++kk) {
        float xv[4], w0[4], w1[4];
        *(float4*)xv = *(const float4*)&xT[kk][ty << 2];
        *(float4*)w0 = *(const float4*)&bT[kk][tx << 2];
        *(float4*)w1 = *(const float4*)&bT[kk][64 + (tx << 2)];
#pragma unroll
        for (int i = 0; i < 4; ++i) {
#pragma unroll
          for (int j = 0; j < 4; ++j) {
            acc[i][j]     = fmaf(xv[i], w0[j], acc[i][j]);
            acc[i][4 + j] = fmaf(xv[i], w1[j], acc[i][4 + j]);
          }
        }
      }
    }
    // epilogue: + b1, silu, store h (two float4 per token)
#pragma unroll
    for (int i = 0; i < 4; ++i) {
      const int tok = tok0 + (ty << 2) + i;
      float o0[4], o1[4];
#pragma unroll
      for (int j = 0; j < 4; ++j) {
        const float a0 = acc[i][j] + b1[col0 + (tx << 2) + j];
        o0[j] = a0 / (1.f + expf(-a0));
        const float a1 = acc[i][4 + j] + b1[col0 + 64 + (tx << 2) + j];
        o1[j] = a1 / (1.f + expf(-a1));
      }
      *(float4*)(h + (size_t)tok * H_DIM + col0 + (tx << 2)) = *(float4*)o0;
      *(float4*)(h + (size_t)tok * H_DIM + col0 + 64 + (tx << 2)) = *(float4*)o1;
    }
  } else {
    // low path: 64 tok x 80 col, acc 4x5 (tx = r index 0..15, cols j*16+tx)
    float acc[4][5];
#pragma unroll
    for (int i = 0; i < 4; ++i)
#pragma unroll
      for (int j = 0; j < 5; ++j) acc[i][j] = 0.f;

    for (int k0 = 0; k0 < D_DIM; k0 += 32) {
      __syncthreads();
#pragma unroll
      for (int p = 0; p < 2; ++p) {
        const int s = sr + (p << 5);
        float xv[4];
        *(float4*)xv = *(const float4*)(x + (size_t)(tok0 + s) * D_DIM + k0 + sk);
#pragma unroll
        for (int c = 0; c < 4; ++c) xT[sk + c][s] = xv[c];
      }
      // stage A' tile [32 k][80 col]; col c=g*4+u maps e=c>>4, r=c&15
      for (int idx = t; idx < 640; idx += 256) {
        const int kk = idx / 20;
        const int g = idx % 20;
        const int e = g >> 2;
        const int r4 = (g & 3) << 2;
        *(float4*)&bT[kk][g << 2] =
            *(const float4*)(A + (size_t)e * (D_DIM * R_DIM) +
                             (size_t)(k0 + kk) * R_DIM + r4);
      }
      __syncthreads();
#pragma unroll
      for (int kk = 0; kk < 32; ++kk) {
        float xv[4];
        *(float4*)xv = *(const float4*)&xT[kk][ty << 2];
#pragma unroll
        for (int j = 0; j < 5; ++j) {
          const float aj = bT[kk][(j << 4) + tx];
#pragma unroll
          for (int i = 0; i < 4; ++i) acc[i][j] = fmaf(xv[i], aj, acc[i][j]);
        }
      }
    }
#pragma unroll
    for (int i = 0; i < 4; ++i) {
      const int tok = tok0 + (ty << 2) + i;
#pragma unroll
      for (int j = 0; j < 5; ++j)
        P[(size_t)tok * ER + (j << 4) + tx] = acc[i][j];
    }
  }
}

// ---------------------------------------------------------------------------
// route: logits = h@W2 + b2, top-2, pair-normalized weights; scales P in
// place by (selected ? 2*w : 0).  4 lanes per token, 64 tokens/block.
// ---------------------------------------------------------------------------
__global__ __launch_bounds__(256) void route_kernel(
    const float* __restrict__ h, const float* __restrict__ W2,
    const float* __restrict__ b2, float* __restrict__ P) {
  __shared__ float w2s[H_DIM * E_NUM];
  const int t = threadIdx.x;
  for (int i = t; i < H_DIM * E_NUM; i += 256) w2s[i] = W2[i];
  __syncthreads();

  const int tok = blockIdx.x * 64 + (t >> 2);
  const int part = t & 3;
  float p[5] = {0.f, 0.f, 0.f, 0.f, 0.f};
  const float* hr = h + (size_t)tok * H_DIM + part * 64;
#pragma unroll
  for (int i = 0; i < 16; ++i) {
    float hv[4];
    *(float4*)hv = *(const float4*)(hr + (i << 2));
#pragma unroll
    for (int u = 0; u < 4; ++u) {
      const int c = part * 64 + (i << 2) + u;
#pragma unroll
      for (int e = 0; e < 5; ++e) p[e] = fmaf(hv[u], w2s[c * 5 + e], p[e]);
    }
  }
#pragma unroll
  for (int e = 0; e < 5; ++e) {
    p[e] += __shfl_xor(p[e], 1, 64);
    p[e] += __shfl_xor(p[e], 2, 64);
    p[e] += b2[e];
  }
  // top-2 by logits; strict > matches jax.lax.top_k tie order.
  int e0 = 0;
#pragma unroll
  for (int e = 1; e < 5; ++e) if (p[e] > p[e0]) e0 = e;
  int e1 = (e0 == 0) ? 1 : 0;
#pragma unroll
  for (int e = 0; e < 5; ++e) if (e != e0 && p[e] > p[e1]) e1 = e;
  const float q = expf(p[e1] - p[e0]);   // <= 1, stable
  const float s0 = 2.f / (1.f + q);      // SCALING * w0_normalized
  const float s1 = q * s0;               // SCALING * w1_normalized

  float* pr = P + (size_t)tok * ER + part * 20;
#pragma unroll
  for (int g = 0; g < 5; ++g) {
    float pv[4];
    *(float4*)pv = *(const float4*)(pr + (g << 2));
#pragma unroll
    for (int u = 0; u < 4; ++u) {
      const int e = (part * 20 + (g << 2) + u) >> 4;
      const float s = (e == e0) ? s0 : ((e == e1) ? s1 : 0.f);
      pv[u] *= s;
    }
    *(float4*)(pr + (g << 2)) = *(float4*)pv;
  }
}

// ---------------------------------------------------------------------------
// combine: out = base + P[N,80] @ B[80,2048].  P pre-scaled by route_kernel.
// P rows read via wave-uniform addresses (scalar loads), B via float4.
// ---------------------------------------------------------------------------
__global__ __launch_bounds__(256) void combine_kernel(
    const float* __restrict__ P, const float* __restrict__ Bm,
    const float* __restrict__ base, float* __restrict__ out) {
  const int t = threadIdx.x;
  const int wg = __builtin_amdgcn_readfirstlane(t >> 6);  // wave-uniform
  const int c4 = ((blockIdx.x & 7) << 8) + ((t & 63) << 2);
  const int tok0 = ((blockIdx.x >> 3) << 6) + (wg << 4);

  float4 acc[16];
#pragma unroll
  for (int i = 0; i < 16; ++i) acc[i] = make_float4(0.f, 0.f, 0.f, 0.f);

  for (int k0 = 0; k0 < ER; k0 += 4) {
    const float4 bv0 = *(const float4*)(Bm + (size_t)(k0 + 0) * D_DIM + c4);
    const float4 bv1 = *(const float4*)(Bm + (size_t)(k0 + 1) * D_DIM + c4);
    const float4 bv2 = *(const float4*)(Bm + (size_t)(k0 + 2) * D_DIM + c4);
    const float4 bv3 = *(const float4*)(Bm + (size_t)(k0 + 3) * D_DIM + c4);
#pragma unroll
    for (int i = 0; i < 16; ++i) {
      const float* pr = P + (size_t)(tok0 + i) * ER + k0;  // uniform -> s_load
      const float p0 = pr[0], p1 = pr[1], p2 = pr[2], p3 = pr[3];
      acc[i].x = fmaf(p0, bv0.x, fmaf(p1, bv1.x, fmaf(p2, bv2.x, fmaf(p3, bv3.x, acc[i].x))));
      acc[i].y = fmaf(p0, bv0.y, fmaf(p1, bv1.y, fmaf(p2, bv2.y, fmaf(p3, bv3.y, acc[i].y))));
      acc[i].z = fmaf(p0, bv0.z, fmaf(p1, bv1.z, fmaf(p2, bv2.z, fmaf(p3, bv3.z, acc[i].z))));
      acc[i].w = fmaf(p0, bv0.w, fmaf(p1, bv1.w, fmaf(p2, bv2.w, fmaf(p3, bv3.w, acc[i].w))));
    }
  }

#pragma unroll
  for (int i = 0; i < 16; ++i) {
    const size_t o = (size_t)(tok0 + i) * D_DIM + c4;
    const float4 b = *(const float4*)(base + o);
    float4 r;
    r.x = acc[i].x + b.x;
    r.y = acc[i].y + b.y;
    r.z = acc[i].z + b.z;
    r.w = acc[i].w + b.w;
    *(float4*)(out + o) = r;
  }
}

// ---------------------------------------------------------------------------
extern "C" void kernel_launch(void* const* d_in, const int* in_sizes, int n_in,
                              void* d_out, int out_size, void* d_ws,
                              size_t ws_size, hipStream_t stream) {
  const float* x  = (const float*)d_in[0];
  const float* bo = (const float*)d_in[1];
  const float* A  = (const float*)d_in[2];
  const float* Bm = (const float*)d_in[3];
  const float* W1 = (const float*)d_in[4];
  const float* b1 = (const float*)d_in[5];
  const float* W2 = (const float*)d_in[6];
  const float* b2 = (const float*)d_in[7];
  float* out = (float*)d_out;

  char* ws = (char*)d_ws;
  float* h = (float*)ws;                     // [N][256] f32 = 16 MiB
  float* P = (float*)(ws + 16777216);        // [N][80]  f32 = 5.25 MiB

  xgemm_kernel<<<dim3(N_TOK / 64, 3), 256, 0, stream>>>(x, W1, b1, A, h, P);
  route_kernel<<<N_TOK / 64, 256, 0, stream>>>(h, W2, b2, P);
  combine_kernel<<<(N_TOK / 64) * (D_DIM / 256), 256, 0, stream>>>(P, Bm, bo, out);
}